// Round 6
// baseline (354.131 us; speedup 1.0000x reference)
//
#include <hip/hip_runtime.h>

// N = 16384 rows, D_TS = 1022 ts cols, D = 1024 total cols, C = 2, GAMMA = 0.1
// Reference:
//   x = concat(ts, meta0, meta1)                 [N, 1024]
//   S[d] = sum_i x[i,d]; Q[d] = sum_i x[i,d]^2
//   pairwise_sq[i,d] = N*x^2 - 2*x*S[d] + Q[d]
//   out = exp(-GAMMA*pairwise_sq) @ w.T + b      [N, 2] fp32
//
// Round-6: single kernel with MANUAL grid barriers (round-5 cooperative
// launch is not graph-capturable -> kernel never ran). 1024 blocks x 256 thr;
// __launch_bounds__(256,4) caps VGPR at 128 and LDS is 38.9 KB -> exactly
// 4 blocks/CU x 256 CU = 1024 co-resident, so a spin barrier cannot deadlock.
// Barrier counters live in d_ws and are zeroed by an 8-B memset every call
// (ws is poisoned 0xAA once and never re-poisoned between replays).
//   Phase 1: block b owns rows b*16..+15; per-thread 4-col partials; rows
//            0..8 staged in LDS (36 KB) for reuse across the barrier.
//   Phase 2: 64 blocks reduce psum/psq[1024][1024] -> colS4/colQ4[4][1024].
//   Phase 3: per-lane register constants; rows 0..8 from LDS, 9..15 from L3.
// History: r2 atomics=44us, r4 3-kernel=34us, r5 cooperative=FAIL.

#define NROWS   16384
#define DTS     1022
#define DTOT    1024
#define NBLK    1024
#define RPB     16                  // rows per block
#define CACHED  9                   // rows staged in LDS
#define GAMMA_F 0.1f

__device__ __forceinline__ void grid_barrier(unsigned* cnt, unsigned total) {
  __threadfence();                  // make prior global writes visible
  __syncthreads();                  // whole block done with its phase
  if (threadIdx.x == 0) {
    __hip_atomic_fetch_add(cnt, 1u, __ATOMIC_ACQ_REL,
                           __HIP_MEMORY_SCOPE_AGENT);
    while (__hip_atomic_load(cnt, __ATOMIC_ACQUIRE,
                             __HIP_MEMORY_SCOPE_AGENT) < total) {
      __builtin_amdgcn_s_sleep(2);  // back off the L2 atomic line
    }
  }
  __syncthreads();
}

__global__ __launch_bounds__(256, 4) void svm_fused(
    const float* __restrict__ ts, const float* __restrict__ m0,
    const float* __restrict__ m1, const float* __restrict__ w,
    const float* __restrict__ bias, float* __restrict__ psum,
    float* __restrict__ psq, float* __restrict__ colS4,
    float* __restrict__ colQ4, unsigned* __restrict__ barrier_cnt,
    float* __restrict__ out) {
  __shared__ float rowc[CACHED][DTOT];          // 36864 B row cache
  __shared__ float ls[4][64], lq[4][64];        // 2048 B phase-2 scratch

  const int b = blockIdx.x;
  const int t = threadIdx.x;
  const int r0 = b * RPB;

  // ---------------- Phase 1: partial column sums + LDS row staging ---------
  {
    const int dA = 2 * t;           // cols 0..510   (even)
    const int dB = 512 + 2 * t;     // cols 512..1022 (1022 -> meta)
    float sA0 = 0.f, sA1 = 0.f, qA0 = 0.f, qA1 = 0.f;
    float sB0 = 0.f, sB1 = 0.f, qB0 = 0.f, qB1 = 0.f;
#pragma unroll 4
    for (int r = 0; r < RPB; ++r) {
      const int i = r0 + r;
      const float* row = ts + (size_t)i * DTS;
      float2 va = *reinterpret_cast<const float2*>(row + dA);
      float2 vb;
      if (dB < DTS) {
        vb = *reinterpret_cast<const float2*>(row + dB);
      } else {                       // dB == 1022: metadata columns
        vb = make_float2(m0[i], m1[i]);
      }
      sA0 += va.x; sA1 += va.y; qA0 += va.x * va.x; qA1 += va.y * va.y;
      sB0 += vb.x; sB1 += vb.y; qB0 += vb.x * vb.x; qB1 += vb.y * vb.y;
      if (r < CACHED) {
        *reinterpret_cast<float2*>(&rowc[r][dA]) = va;
        *reinterpret_cast<float2*>(&rowc[r][dB]) = vb;
      }
    }
    *reinterpret_cast<float2*>(psum + b * DTOT + dA) = make_float2(sA0, sA1);
    *reinterpret_cast<float2*>(psum + b * DTOT + dB) = make_float2(sB0, sB1);
    *reinterpret_cast<float2*>(psq  + b * DTOT + dA) = make_float2(qA0, qA1);
    *reinterpret_cast<float2*>(psq  + b * DTOT + dB) = make_float2(qB0, qB1);
  }

  grid_barrier(&barrier_cnt[0], NBLK);

  // ---------------- Phase 2: reduce 1024 chunks -> 4 quarters --------------
  // 64 active blocks: col-group g = b&15 (64 cols), chunk-quarter q = b>>4.
  if (b < 64) {
    const int g = b & 15, q = b >> 4;
    const int wv = t >> 6, ln = t & 63;
    const int c = g * 64 + ln;                  // 0..1023
    float s = 0.f, qq = 0.f;
#pragma unroll 8
    for (int ch = q * 256 + wv; ch < (q + 1) * 256; ch += 4) {
      s  += psum[ch * DTOT + c];
      qq += psq[ch * DTOT + c];
    }
    ls[wv][ln] = s;
    lq[wv][ln] = qq;
    __syncthreads();
    if (wv == 0) {
      colS4[q * DTOT + c] = ls[0][ln] + ls[1][ln] + ls[2][ln] + ls[3][ln];
      colQ4[q * DTOT + c] = lq[0][ln] + lq[1][ln] + lq[2][ln] + lq[3][ln];
    }
  }

  grid_barrier(&barrier_cnt[1], NBLK);

  // ---------------- Phase 3: fused feat + GEMV -----------------------------
  {
    const int wv = t >> 6, ln = t & 63;
    const float b0 = bias[0], b1 = bias[1];
    const float c2 = -GAMMA_F * (float)NROWS;   // -gamma*N

    // Per-lane register constants for its 16 fixed columns.
    float c1x[8], c1y[8], c0x[8], c0y[8];
    float w0x[8], w0y[8], w1x[8], w1y[8];
#pragma unroll
    for (int k = 0; k < 8; ++k) {
      const int d = k * 128 + ln * 2;           // even, 0..1022
      float sx = 0.f, sy = 0.f, qx = 0.f, qy = 0.f;
#pragma unroll
      for (int q = 0; q < 4; ++q) {
        float2 cs = *reinterpret_cast<const float2*>(colS4 + q * DTOT + d);
        float2 cq = *reinterpret_cast<const float2*>(colQ4 + q * DTOT + d);
        sx += cs.x; sy += cs.y; qx += cq.x; qy += cq.y;
      }
      c1x[k] = 2.0f * GAMMA_F * sx;
      c1y[k] = 2.0f * GAMMA_F * sy;
      c0x[k] = -GAMMA_F * qx;
      c0y[k] = -GAMMA_F * qy;
      float2 v0 = *reinterpret_cast<const float2*>(w + d);
      float2 v1 = *reinterpret_cast<const float2*>(w + DTOT + d);
      w0x[k] = v0.x; w0y[k] = v0.y;
      w1x[k] = v1.x; w1y[k] = v1.y;
    }

#pragma unroll
    for (int j = 0; j < 4; ++j) {
      const int rr = wv * 4 + j;                // 0..15 (wave-uniform)
      const int i = r0 + rr;
      float acc0 = 0.f, acc1 = 0.f;
      if (rr < CACHED) {                        // LDS-resident row
#pragma unroll
        for (int k = 0; k < 8; ++k) {
          const int d = k * 128 + ln * 2;
          float2 v = *reinterpret_cast<const float2*>(&rowc[rr][d]);
          const float p0 = (c2 * v.x + c1x[k]) * v.x + c0x[k];
          const float p1 = (c2 * v.y + c1y[k]) * v.y + c0y[k];
          const float f0 = __expf(p0);
          const float f1 = __expf(p1);
          acc0 += f0 * w0x[k] + f1 * w0y[k];
          acc1 += f0 * w1x[k] + f1 * w1y[k];
        }
      } else {                                  // global (L3) row
        const float* row = ts + (size_t)i * DTS;
#pragma unroll
        for (int k = 0; k < 8; ++k) {
          const int d = k * 128 + ln * 2;
          float x0, x1;
          if (d < DTS) {
            float2 v = *reinterpret_cast<const float2*>(row + d);
            x0 = v.x; x1 = v.y;
          } else {                              // d == 1022 -> meta columns
            x0 = m0[i]; x1 = m1[i];
          }
          const float p0 = (c2 * x0 + c1x[k]) * x0 + c0x[k];
          const float p1 = (c2 * x1 + c1y[k]) * x1 + c0y[k];
          const float f0 = __expf(p0);
          const float f1 = __expf(p1);
          acc0 += f0 * w0x[k] + f1 * w0y[k];
          acc1 += f0 * w1x[k] + f1 * w1y[k];
        }
      }
#pragma unroll
      for (int off = 32; off; off >>= 1) {
        acc0 += __shfl_down(acc0, off);
        acc1 += __shfl_down(acc1, off);
      }
      if (ln == 0) {
        out[i * 2 + 0] = acc0 + b0;
        out[i * 2 + 1] = acc1 + b1;
      }
    }
  }
}

extern "C" void kernel_launch(void* const* d_in, const int* in_sizes, int n_in,
                              void* d_out, int out_size, void* d_ws,
                              size_t ws_size, hipStream_t stream) {
  const float* ts = (const float*)d_in[0];   // [16384, 1022]
  const float* m0 = (const float*)d_in[1];   // [16384]
  const float* m1 = (const float*)d_in[2];   // [16384]
  const float* w  = (const float*)d_in[3];   // [2, 1024]
  const float* bb = (const float*)d_in[4];   // [2]
  float* out = (float*)d_out;                // [16384, 2]

  float* psum  = (float*)d_ws;               // [1024][1024]
  float* psq   = psum + NBLK * DTOT;         // [1024][1024]
  float* colS4 = psq + NBLK * DTOT;          // [4][1024]
  float* colQ4 = colS4 + 4 * DTOT;           // [4][1024]
  unsigned* barrier_cnt = (unsigned*)(colQ4 + 4 * DTOT);  // 2 counters

  // Re-zero barrier counters every call (ws poisoned once, never restored).
  hipMemsetAsync(barrier_cnt, 0, 2 * sizeof(unsigned), stream);
  svm_fused<<<dim3(NBLK), dim3(256), 0, stream>>>(
      ts, m0, m1, w, bb, psum, psq, colS4, colQ4, barrier_cnt, out);
}

// Round 7
// 217.839 us; speedup vs baseline: 1.6257x; 1.6257x over previous
//
#include <hip/hip_runtime.h>

// N = 16384 rows, D_TS = 1022 ts cols, D = 1024 total cols, C = 2, GAMMA = 0.1
// Reference:
//   x = concat(ts, meta0, meta1)                 [N, 1024]
//   S[d] = sum_i x[i,d]; Q[d] = sum_i x[i,d]^2
//   pairwise_sq[i,d] = N*x^2 - 2*x*S[d] + Q[d]
//   out = exp(-GAMMA*pairwise_sq) @ w.T + b      [N, 2] fp32
//
// Round-7: single kernel, manual grid barrier FIXED (round-6's 354us was the
// ACQUIRE-per-poll spin: every poll emitted buffer_inv, wiping L2 chip-wide).
// Now: RELAXED polls (sc1 fabric reads, no cache ops) + ONE acquire at exit.
// Data strategy: each thread owns 4 fixed columns {2t,2t+1,512+2t,513+2t};
// phase 1 reads its 16 rows x 4 cols ONCE and keeps them in 64 VGPRs across
// the barrier -> phase 3 is compute-only (no ts re-read at all). Phase-3
// reduction = wave butterfly + 512B LDS cross-wave combine (block-wide).
// 1024 blocks x 256 thr; __launch_bounds__(256,4) caps VGPR at 128 and LDS
// is ~2.5 KB -> 4 blocks/CU x 256 CU = 1024 co-resident, barrier safe.
// History: r2 atomics=44us, r4 3-kernel=34us, r5 coop=FAIL, r6 barrier=354us.

#define NROWS   16384
#define DTS     1022
#define DTOT    1024
#define NBLK    1024
#define RPB     16                  // rows per block (all register-cached)
#define GAMMA_F 0.1f

__device__ __forceinline__ void grid_barrier(unsigned* cnt, unsigned total) {
  __syncthreads();                  // block done with its phase
  if (threadIdx.x == 0) {
    // Release: orders prior global stores (psum/colS4) before the increment;
    // emits one L2 writeback so other XCDs can see our data.
    __hip_atomic_fetch_add(cnt, 1u, __ATOMIC_RELEASE,
                           __HIP_MEMORY_SCOPE_AGENT);
    // Relaxed polls: fabric-coherent loads, NO per-poll cache invalidation
    // (round-6 bug). Every 32 polls issue one acquire as a forward-progress
    // hedge in case a relaxed poll is ever served from a stale line.
    int k = 0;
    while (__hip_atomic_load(cnt, __ATOMIC_RELAXED,
                             __HIP_MEMORY_SCOPE_AGENT) < total) {
      __builtin_amdgcn_s_sleep(8);
      if ((++k & 31) == 31) {
        (void)__hip_atomic_load(cnt, __ATOMIC_ACQUIRE,
                                __HIP_MEMORY_SCOPE_AGENT);
      }
    }
    // Acquire: one L1/L2 invalidate so subsequent reads see remote writes.
    (void)__hip_atomic_load(cnt, __ATOMIC_ACQUIRE, __HIP_MEMORY_SCOPE_AGENT);
  }
  __syncthreads();
}

__global__ __launch_bounds__(256, 4) void svm_fused(
    const float* __restrict__ ts, const float* __restrict__ m0,
    const float* __restrict__ m1, const float* __restrict__ w,
    const float* __restrict__ bias, float* __restrict__ psum,
    float* __restrict__ psq, float* __restrict__ colS4,
    float* __restrict__ colQ4, unsigned* __restrict__ bar,
    float* __restrict__ out) {
  __shared__ float red[RPB][4][2];        // 512 B: per-row per-wave partials
  __shared__ float ls[4][64], lq[4][64];  // 2 KB: phase-2 scratch

  const int b  = blockIdx.x;
  const int t  = threadIdx.x;
  const int wv = t >> 6, ln = t & 63;
  const int r0 = b * RPB;
  const int cA = 2 * t;                   // cols 0..510   (even)
  const int cB = 512 + 2 * t;             // cols 512..1022 (1022 -> meta)

  // ---- Phase 1: read this block's 16 rows once; keep all 4 cols/row in
  //      registers (static unroll -> no scratch); accumulate column partials.
  float2 ra[RPB], rb[RPB];
  float sA0 = 0.f, sA1 = 0.f, qA0 = 0.f, qA1 = 0.f;
  float sB0 = 0.f, sB1 = 0.f, qB0 = 0.f, qB1 = 0.f;
#pragma unroll
  for (int r = 0; r < RPB; ++r) {
    const int i = r0 + r;
    const float* row = ts + (size_t)i * DTS;
    float2 va = *reinterpret_cast<const float2*>(row + cA);
    float2 vb;
    if (cB < DTS) {
      vb = *reinterpret_cast<const float2*>(row + cB);
    } else {                              // cB == 1022: metadata columns
      vb = make_float2(m0[i], m1[i]);
    }
    ra[r] = va;
    rb[r] = vb;
    sA0 += va.x; sA1 += va.y; qA0 += va.x * va.x; qA1 += va.y * va.y;
    sB0 += vb.x; sB1 += vb.y; qB0 += vb.x * vb.x; qB1 += vb.y * vb.y;
  }
  *reinterpret_cast<float2*>(psum + b * DTOT + cA) = make_float2(sA0, sA1);
  *reinterpret_cast<float2*>(psum + b * DTOT + cB) = make_float2(sB0, sB1);
  *reinterpret_cast<float2*>(psq  + b * DTOT + cA) = make_float2(qA0, qA1);
  *reinterpret_cast<float2*>(psq  + b * DTOT + cB) = make_float2(qB0, qB1);

  grid_barrier(&bar[0], NBLK);

  // ---- Phase 2: 64 blocks reduce psum/psq[1024][1024] -> quarters [4][1024].
  // Block b<64: col-group g=b&15 (64 cols), chunk-quarter q=b>>4 (256 chunks).
  if (b < 64) {
    const int g = b & 15, q = b >> 4;
    const int c = g * 64 + ln;            // coalesced: lane <-> column
    float s = 0.f, qq = 0.f;
#pragma unroll 16
    for (int ch = q * 256 + wv; ch < (q + 1) * 256; ch += 4) {
      s  += psum[ch * DTOT + c];
      qq += psq[ch * DTOT + c];
    }
    ls[wv][ln] = s;
    lq[wv][ln] = qq;
    __syncthreads();
    if (wv == 0) {
      colS4[q * DTOT + c] = ls[0][ln] + ls[1][ln] + ls[2][ln] + ls[3][ln];
      colQ4[q * DTOT + c] = lq[0][ln] + lq[1][ln] + lq[2][ln] + lq[3][ln];
    }
  }

  grid_barrier(&bar[1], NBLK);

  // ---- Phase 3: compute-only. Fold quarters for this thread's 4 columns,
  //      then 16 rows of exp+dot from the register cache; block-wide reduce.
  float fsA0 = 0.f, fsA1 = 0.f, fsB0 = 0.f, fsB1 = 0.f;
  float fqA0 = 0.f, fqA1 = 0.f, fqB0 = 0.f, fqB1 = 0.f;
#pragma unroll
  for (int q = 0; q < 4; ++q) {
    float2 x;
    x = *reinterpret_cast<const float2*>(colS4 + q * DTOT + cA);
    fsA0 += x.x; fsA1 += x.y;
    x = *reinterpret_cast<const float2*>(colS4 + q * DTOT + cB);
    fsB0 += x.x; fsB1 += x.y;
    x = *reinterpret_cast<const float2*>(colQ4 + q * DTOT + cA);
    fqA0 += x.x; fqA1 += x.y;
    x = *reinterpret_cast<const float2*>(colQ4 + q * DTOT + cB);
    fqB0 += x.x; fqB1 += x.y;
  }
  const float c2 = -GAMMA_F * (float)NROWS;     // -gamma*N
  const float c1A0 = 2.f * GAMMA_F * fsA0, c1A1 = 2.f * GAMMA_F * fsA1;
  const float c1B0 = 2.f * GAMMA_F * fsB0, c1B1 = 2.f * GAMMA_F * fsB1;
  const float c0A0 = -GAMMA_F * fqA0, c0A1 = -GAMMA_F * fqA1;
  const float c0B0 = -GAMMA_F * fqB0, c0B1 = -GAMMA_F * fqB1;
  const float2 w0A = *reinterpret_cast<const float2*>(w + cA);
  const float2 w0B = *reinterpret_cast<const float2*>(w + cB);
  const float2 w1A = *reinterpret_cast<const float2*>(w + DTOT + cA);
  const float2 w1B = *reinterpret_cast<const float2*>(w + DTOT + cB);

#pragma unroll
  for (int r = 0; r < RPB; ++r) {
    const float2 va = ra[r], vb = rb[r];
    const float f0 = __expf((c2 * va.x + c1A0) * va.x + c0A0);
    const float f1 = __expf((c2 * va.y + c1A1) * va.y + c0A1);
    const float f2 = __expf((c2 * vb.x + c1B0) * vb.x + c0B0);
    const float f3 = __expf((c2 * vb.y + c1B1) * vb.y + c0B1);
    float a0 = f0 * w0A.x + f1 * w0A.y + f2 * w0B.x + f3 * w0B.y;
    float a1 = f0 * w1A.x + f1 * w1A.y + f2 * w1B.x + f3 * w1B.y;
#pragma unroll
    for (int off = 32; off; off >>= 1) {
      a0 += __shfl_down(a0, off);
      a1 += __shfl_down(a1, off);
    }
    if (ln == 0) {
      red[r][wv][0] = a0;
      red[r][wv][1] = a1;
    }
  }
  __syncthreads();
  if (t < RPB) {                          // 16 threads finalize 16 rows
    const float o0 =
        red[t][0][0] + red[t][1][0] + red[t][2][0] + red[t][3][0] + bias[0];
    const float o1 =
        red[t][0][1] + red[t][1][1] + red[t][2][1] + red[t][3][1] + bias[1];
    out[(r0 + t) * 2 + 0] = o0;
    out[(r0 + t) * 2 + 1] = o1;
  }
}

extern "C" void kernel_launch(void* const* d_in, const int* in_sizes, int n_in,
                              void* d_out, int out_size, void* d_ws,
                              size_t ws_size, hipStream_t stream) {
  const float* ts = (const float*)d_in[0];   // [16384, 1022]
  const float* m0 = (const float*)d_in[1];   // [16384]
  const float* m1 = (const float*)d_in[2];   // [16384]
  const float* w  = (const float*)d_in[3];   // [2, 1024]
  const float* bb = (const float*)d_in[4];   // [2]
  float* out = (float*)d_out;                // [16384, 2]

  float* psum  = (float*)d_ws;               // [1024][1024]
  float* psq   = psum + NBLK * DTOT;         // [1024][1024]
  float* colS4 = psq + NBLK * DTOT;          // [4][1024]
  float* colQ4 = colS4 + 4 * DTOT;           // [4][1024]
  unsigned* bar = (unsigned*)(colQ4 + 4 * DTOT);  // 2 counters

  // Re-zero barrier counters every call (ws poisoned once, never restored).
  hipMemsetAsync(bar, 0, 2 * sizeof(unsigned), stream);
  svm_fused<<<dim3(NBLK), dim3(256), 0, stream>>>(
      ts, m0, m1, w, bb, psum, psq, colS4, colQ4, bar, out);
}

// Round 8
// 134.295 us; speedup vs baseline: 2.6370x; 1.6221x over previous
//
#include <hip/hip_runtime.h>

// N = 16384 rows, D_TS = 1022 ts cols, D = 1024 total cols, C = 2, GAMMA = 0.1
// Reference:
//   x = concat(ts, meta0, meta1)                 [N, 1024]
//   S[d] = sum_i x[i,d]; Q[d] = sum_i x[i,d]^2
//   pairwise_sq[i,d] = N*x^2 - 2*x*S[d] + Q[d]
//   out = exp(-GAMMA*pairwise_sq) @ w.T + b      [N, 2] fp32
//
// Round-8: kill ALL cache-maintenance in the barrier. r6 (354us) = acquire
// per poll -> buffer_inv storm; r7 (218us) = release/acquire per block ->
// 2048 whole-L2 wbl2/inv ops. Now:
//   * cross-barrier data written with agent-scope RELAXED atomic stores
//     (sc1 write-through -> never dirty in L2, nothing to write back)
//   * barrier = s_waitcnt vmcnt(0) + relaxed fetch_add + relaxed spin
//     (zero wbl2/inv in the whole kernel)
//   * consumers use normal cached loads: dispatch-start acquire invalidated
//     L1/L2, and no cached access touches psum/colS4 before its producer
//     phase, so first read misses to IF$ and sees the write-through data.
// 1024 blocks x 256 thr, __launch_bounds__(256,4), LDS 2.5 KB -> 4 blocks/CU
// x 256 CU = 1024 co-resident; spin barrier cannot deadlock.
// History: r2 atomics=44us, r4 3-kernel=34us, r5 coop=FAIL, r6=354, r7=218.

#define NROWS   16384
#define DTS     1022
#define DTOT    1024
#define NBLK    1024
#define RPB     16                  // rows per block
#define GAMMA_F 0.1f

// Agent-scope relaxed (write-through, no cache maintenance) 8-byte store.
__device__ __forceinline__ void st_f2_agent(float* p, float2 v) {
  __hip_atomic_store(reinterpret_cast<unsigned long long*>(p),
                     __builtin_bit_cast(unsigned long long, v),
                     __ATOMIC_RELAXED, __HIP_MEMORY_SCOPE_AGENT);
}

__device__ __forceinline__ void grid_barrier(unsigned* cnt, unsigned total) {
  __syncthreads();                  // block done with its phase
  if (threadIdx.x == 0) {
    // Drain our write-through stores to the coherence point, then count in.
    asm volatile("s_waitcnt vmcnt(0)" ::: "memory");
    __hip_atomic_fetch_add(cnt, 1u, __ATOMIC_RELAXED,
                           __HIP_MEMORY_SCOPE_AGENT);
    // Relaxed spin: fabric reads, no cache ops, gentle backoff.
    while (__hip_atomic_load(cnt, __ATOMIC_RELAXED,
                             __HIP_MEMORY_SCOPE_AGENT) < total) {
      __builtin_amdgcn_s_sleep(2);
    }
  }
  __syncthreads();
}

__global__ __launch_bounds__(256, 4) void svm_fused(
    const float* __restrict__ ts, const float* __restrict__ m0,
    const float* __restrict__ m1, const float* __restrict__ w,
    const float* __restrict__ bias, float* __restrict__ psum,
    float* __restrict__ psq, float* __restrict__ colS4,
    float* __restrict__ colQ4, unsigned* __restrict__ bar,
    float* __restrict__ out) {
  __shared__ float red[RPB][4][2];        // 512 B: per-row per-wave partials
  __shared__ float ls[4][64], lq[4][64];  // 2 KB: phase-2 scratch

  const int b  = blockIdx.x;
  const int t  = threadIdx.x;
  const int wv = t >> 6, ln = t & 63;
  const int r0 = b * RPB;
  const int cA = 2 * t;                   // cols 0..510   (even)
  const int cB = 512 + 2 * t;             // cols 512..1022 (1022 -> meta)

  // ---- Phase 1: read this block's 16 rows; keep 4 cols/row in registers
  //      (compiler may instead re-load from L3 in phase 3 -- acceptable);
  //      accumulate column partials; write-through to psum/psq.
  float2 ra[RPB], rb[RPB];
  float sA0 = 0.f, sA1 = 0.f, qA0 = 0.f, qA1 = 0.f;
  float sB0 = 0.f, sB1 = 0.f, qB0 = 0.f, qB1 = 0.f;
#pragma unroll
  for (int r = 0; r < RPB; ++r) {
    const int i = r0 + r;
    const float* row = ts + (size_t)i * DTS;
    float2 va = *reinterpret_cast<const float2*>(row + cA);
    float2 vb;
    if (cB < DTS) {
      vb = *reinterpret_cast<const float2*>(row + cB);
    } else {                              // cB == 1022: metadata columns
      vb = make_float2(m0[i], m1[i]);
    }
    ra[r] = va;
    rb[r] = vb;
    sA0 += va.x; sA1 += va.y; qA0 += va.x * va.x; qA1 += va.y * va.y;
    sB0 += vb.x; sB1 += vb.y; qB0 += vb.x * vb.x; qB1 += vb.y * vb.y;
  }
  st_f2_agent(psum + b * DTOT + cA, make_float2(sA0, sA1));
  st_f2_agent(psum + b * DTOT + cB, make_float2(sB0, sB1));
  st_f2_agent(psq  + b * DTOT + cA, make_float2(qA0, qA1));
  st_f2_agent(psq  + b * DTOT + cB, make_float2(qB0, qB1));

  grid_barrier(&bar[0], NBLK);

  // ---- Phase 2: 64 blocks reduce psum/psq[1024][1024] -> quarters [4][1024].
  // Block b<64: col-group g=b&15 (64 cols, lane<->col coalesced), quarter
  // q=b>>4 (256 chunks). Normal cached loads (see header comment).
  if (b < 64) {
    const int g = b & 15, q = b >> 4;
    const int c = g * 64 + ln;
    float s = 0.f, qq = 0.f;
#pragma unroll 16
    for (int ch = q * 256 + wv; ch < (q + 1) * 256; ch += 4) {
      s  += psum[ch * DTOT + c];
      qq += psq[ch * DTOT + c];
    }
    ls[wv][ln] = s;
    lq[wv][ln] = qq;
    __syncthreads();
    if (wv == 0) {
      const float S = ls[0][ln] + ls[1][ln] + ls[2][ln] + ls[3][ln];
      const float Q = lq[0][ln] + lq[1][ln] + lq[2][ln] + lq[3][ln];
      // Write-through so phase-3 consumers (other XCDs) see it.
      __hip_atomic_store(colS4 + q * DTOT + c, S, __ATOMIC_RELAXED,
                         __HIP_MEMORY_SCOPE_AGENT);
      __hip_atomic_store(colQ4 + q * DTOT + c, Q, __ATOMIC_RELAXED,
                         __HIP_MEMORY_SCOPE_AGENT);
    }
  }

  grid_barrier(&bar[1], NBLK);

  // ---- Phase 3: fold quarters for this thread's 4 columns (normal loads:
  //      first touch misses to IF$, then L2-cached broadcast), 16 rows of
  //      exp+dot, block-wide reduce, 16 row-results out.
  float fsA0 = 0.f, fsA1 = 0.f, fsB0 = 0.f, fsB1 = 0.f;
  float fqA0 = 0.f, fqA1 = 0.f, fqB0 = 0.f, fqB1 = 0.f;
#pragma unroll
  for (int q = 0; q < 4; ++q) {
    float2 x;
    x = *reinterpret_cast<const float2*>(colS4 + q * DTOT + cA);
    fsA0 += x.x; fsA1 += x.y;
    x = *reinterpret_cast<const float2*>(colS4 + q * DTOT + cB);
    fsB0 += x.x; fsB1 += x.y;
    x = *reinterpret_cast<const float2*>(colQ4 + q * DTOT + cA);
    fqA0 += x.x; fqA1 += x.y;
    x = *reinterpret_cast<const float2*>(colQ4 + q * DTOT + cB);
    fqB0 += x.x; fqB1 += x.y;
  }
  const float c2 = -GAMMA_F * (float)NROWS;     // -gamma*N
  const float c1A0 = 2.f * GAMMA_F * fsA0, c1A1 = 2.f * GAMMA_F * fsA1;
  const float c1B0 = 2.f * GAMMA_F * fsB0, c1B1 = 2.f * GAMMA_F * fsB1;
  const float c0A0 = -GAMMA_F * fqA0, c0A1 = -GAMMA_F * fqA1;
  const float c0B0 = -GAMMA_F * fqB0, c0B1 = -GAMMA_F * fqB1;
  const float2 w0A = *reinterpret_cast<const float2*>(w + cA);
  const float2 w0B = *reinterpret_cast<const float2*>(w + cB);
  const float2 w1A = *reinterpret_cast<const float2*>(w + DTOT + cA);
  const float2 w1B = *reinterpret_cast<const float2*>(w + DTOT + cB);

#pragma unroll
  for (int r = 0; r < RPB; ++r) {
    const float2 va = ra[r], vb = rb[r];
    const float f0 = __expf((c2 * va.x + c1A0) * va.x + c0A0);
    const float f1 = __expf((c2 * va.y + c1A1) * va.y + c0A1);
    const float f2 = __expf((c2 * vb.x + c1B0) * vb.x + c0B0);
    const float f3 = __expf((c2 * vb.y + c1B1) * vb.y + c0B1);
    float a0 = f0 * w0A.x + f1 * w0A.y + f2 * w0B.x + f3 * w0B.y;
    float a1 = f0 * w1A.x + f1 * w1A.y + f2 * w1B.x + f3 * w1B.y;
#pragma unroll
    for (int off = 32; off; off >>= 1) {
      a0 += __shfl_down(a0, off);
      a1 += __shfl_down(a1, off);
    }
    if (ln == 0) {
      red[r][wv][0] = a0;
      red[r][wv][1] = a1;
    }
  }
  __syncthreads();
  if (t < RPB) {                          // 16 threads finalize 16 rows
    const float o0 =
        red[t][0][0] + red[t][1][0] + red[t][2][0] + red[t][3][0] + bias[0];
    const float o1 =
        red[t][0][1] + red[t][1][1] + red[t][2][1] + red[t][3][1] + bias[1];
    out[(r0 + t) * 2 + 0] = o0;
    out[(r0 + t) * 2 + 1] = o1;
  }
}

extern "C" void kernel_launch(void* const* d_in, const int* in_sizes, int n_in,
                              void* d_out, int out_size, void* d_ws,
                              size_t ws_size, hipStream_t stream) {
  const float* ts = (const float*)d_in[0];   // [16384, 1022]
  const float* m0 = (const float*)d_in[1];   // [16384]
  const float* m1 = (const float*)d_in[2];   // [16384]
  const float* w  = (const float*)d_in[3];   // [2, 1024]
  const float* bb = (const float*)d_in[4];   // [2]
  float* out = (float*)d_out;                // [16384, 2]

  float* psum  = (float*)d_ws;               // [1024][1024]
  float* psq   = psum + NBLK * DTOT;         // [1024][1024]
  float* colS4 = psq + NBLK * DTOT;          // [4][1024]
  float* colQ4 = colS4 + 4 * DTOT;           // [4][1024]
  unsigned* bar = (unsigned*)(colQ4 + 4 * DTOT);  // 2 counters

  // Re-zero barrier counters every call; the memset dispatch's end-of-
  // dispatch release flushes its dirty line before our kernel starts.
  hipMemsetAsync(bar, 0, 2 * sizeof(unsigned), stream);
  svm_fused<<<dim3(NBLK), dim3(256), 0, stream>>>(
      ts, m0, m1, w, bb, psum, psq, colS4, colQ4, bar, out);
}

// Round 9
// 62.228 us; speedup vs baseline: 5.6909x; 2.1581x over previous
//
#include <hip/hip_runtime.h>

// N = 16384 rows, D_TS = 1022 ts cols, D = 1024 total cols, C = 2, GAMMA = 0.1
// Reference:
//   x = concat(ts, meta0, meta1)                 [N, 1024]
//   S[d] = sum_i x[i,d]; Q[d] = sum_i x[i,d]^2
//   pairwise_sq[i,d] = N*x^2 - 2*x*S[d] + Q[d]
//   out = exp(-GAMMA*pairwise_sq) @ w.T + b      [N, 2] fp32
//
// Round-9: hierarchical grid barrier. Barrier history:
//   r6 354us: acquire-per-poll -> buffer_inv storm wiped L2 chip-wide.
//   r7 218us: release/acquire per block -> 2048 whole-L2 wbl2/inv ops.
//   r8 134us: zero cache-maintenance, but 1024 fetch_adds on ONE line are a
//             dependent far-atomic chain (~50ns each) = ~55us per barrier.
//   r9: 32 groups x 32 blocks. Leader RMWs its group line (32-deep chains in
//       parallel across 32 x 128B-strided lines); 32nd arriver RMWs root;
//       all spin RELAXED on root (loads only - no ownership ping-pong).
// Cross-barrier data: agent-scope RELAXED atomic stores (write-through, never
// dirty in L2) + s_waitcnt vmcnt(0) before arrival; consumers use normal
// cached loads (first touch in-dispatch misses to fabric).
// 1024 blocks x 256 thr, __launch_bounds__(256,4), LDS 2.5 KB -> 4 blocks/CU
// x 256 CU = 1024 co-resident; spin barrier cannot deadlock.
// History: r2 atomics=44us, r4 3-kernel=34us, r5 coop=FAIL.

#define NROWS   16384
#define DTS     1022
#define DTOT    1024
#define NBLK    1024
#define RPB     16                  // rows per block
#define GAMMA_F 0.1f
#define NGRP    32                  // barrier groups (32 blocks each)
#define GSTRIDE 32                  // u32 stride between group counters (128B)
#define BARSZ   2048                // u32 slots per barrier instance

// Agent-scope relaxed (write-through, no cache maintenance) 8-byte store.
__device__ __forceinline__ void st_f2_agent(float* p, float2 v) {
  __hip_atomic_store(reinterpret_cast<unsigned long long*>(p),
                     __builtin_bit_cast(unsigned long long, v),
                     __ATOMIC_RELAXED, __HIP_MEMORY_SCOPE_AGENT);
}

// Hierarchical arrival barrier: base points at BARSZ u32 (zeroed pre-launch).
// Layout: group counters at base[g*GSTRIDE], root at base[NGRP*GSTRIDE].
__device__ __forceinline__ void grid_barrier(unsigned* base, int grp) {
  __syncthreads();                  // block done with its phase
  if (threadIdx.x == 0) {
    asm volatile("s_waitcnt vmcnt(0)" ::: "memory");  // drain write-throughs
    unsigned* gcnt = base + grp * GSTRIDE;
    unsigned* root = base + NGRP * GSTRIDE;
    const unsigned old = __hip_atomic_fetch_add(gcnt, 1u, __ATOMIC_RELAXED,
                                                __HIP_MEMORY_SCOPE_AGENT);
    if (old == (NBLK / NGRP) - 1u) {      // last arriver of this group
      __hip_atomic_fetch_add(root, 1u, __ATOMIC_RELAXED,
                             __HIP_MEMORY_SCOPE_AGENT);
    }
    while (__hip_atomic_load(root, __ATOMIC_RELAXED,
                             __HIP_MEMORY_SCOPE_AGENT) < NGRP) {
      __builtin_amdgcn_s_sleep(8);
    }
  }
  __syncthreads();
}

__global__ __launch_bounds__(256, 4) void svm_fused(
    const float* __restrict__ ts, const float* __restrict__ m0,
    const float* __restrict__ m1, const float* __restrict__ w,
    const float* __restrict__ bias, float* __restrict__ psum,
    float* __restrict__ psq, float* __restrict__ colS4,
    float* __restrict__ colQ4, unsigned* __restrict__ bar,
    float* __restrict__ out) {
  __shared__ float red[RPB][4][2];        // 512 B: per-row per-wave partials
  __shared__ float ls[4][64], lq[4][64];  // 2 KB: phase-2 scratch

  const int b  = blockIdx.x;
  const int t  = threadIdx.x;
  const int wv = t >> 6, ln = t & 63;
  const int r0 = b * RPB;
  const int grp = b >> 5;                 // 32 consecutive blocks per group
  const int cA = 2 * t;                   // cols 0..510   (even)
  const int cB = 512 + 2 * t;             // cols 512..1022 (1022 -> meta)

  // ---- Phase 1: read this block's 16 rows; accumulate 4-col partials;
  //      write-through to psum/psq. (Register row-cache declared; compiler
  //      may rematerialize from L3 in phase 3 -- acceptable.)
  float2 ra[RPB], rb[RPB];
  float sA0 = 0.f, sA1 = 0.f, qA0 = 0.f, qA1 = 0.f;
  float sB0 = 0.f, sB1 = 0.f, qB0 = 0.f, qB1 = 0.f;
#pragma unroll
  for (int r = 0; r < RPB; ++r) {
    const int i = r0 + r;
    const float* row = ts + (size_t)i * DTS;
    float2 va = *reinterpret_cast<const float2*>(row + cA);
    float2 vb;
    if (cB < DTS) {
      vb = *reinterpret_cast<const float2*>(row + cB);
    } else {                              // cB == 1022: metadata columns
      vb = make_float2(m0[i], m1[i]);
    }
    ra[r] = va;
    rb[r] = vb;
    sA0 += va.x; sA1 += va.y; qA0 += va.x * va.x; qA1 += va.y * va.y;
    sB0 += vb.x; sB1 += vb.y; qB0 += vb.x * vb.x; qB1 += vb.y * vb.y;
  }
  st_f2_agent(psum + b * DTOT + cA, make_float2(sA0, sA1));
  st_f2_agent(psum + b * DTOT + cB, make_float2(sB0, sB1));
  st_f2_agent(psq  + b * DTOT + cA, make_float2(qA0, qA1));
  st_f2_agent(psq  + b * DTOT + cB, make_float2(qB0, qB1));

  grid_barrier(bar, grp);

  // ---- Phase 2: 64 blocks reduce psum/psq[1024][1024] -> quarters [4][1024].
  // Block b<64: col-group g=b&15 (64 cols, lane<->col coalesced), quarter
  // q=b>>4 (256 chunks). Normal cached loads (first in-dispatch touch).
  if (b < 64) {
    const int g = b & 15, q = b >> 4;
    const int c = g * 64 + ln;
    float s = 0.f, qq = 0.f;
#pragma unroll 16
    for (int ch = q * 256 + wv; ch < (q + 1) * 256; ch += 4) {
      s  += psum[ch * DTOT + c];
      qq += psq[ch * DTOT + c];
    }
    ls[wv][ln] = s;
    lq[wv][ln] = qq;
    __syncthreads();
    if (wv == 0) {
      const float S = ls[0][ln] + ls[1][ln] + ls[2][ln] + ls[3][ln];
      const float Q = lq[0][ln] + lq[1][ln] + lq[2][ln] + lq[3][ln];
      __hip_atomic_store(colS4 + q * DTOT + c, S, __ATOMIC_RELAXED,
                         __HIP_MEMORY_SCOPE_AGENT);
      __hip_atomic_store(colQ4 + q * DTOT + c, Q, __ATOMIC_RELAXED,
                         __HIP_MEMORY_SCOPE_AGENT);
    }
  }

  grid_barrier(bar + BARSZ, grp);

  // ---- Phase 3: fold quarters for this thread's 4 columns, 16 rows of
  //      exp+dot from the register cache, block-wide reduce, 16 rows out.
  float fsA0 = 0.f, fsA1 = 0.f, fsB0 = 0.f, fsB1 = 0.f;
  float fqA0 = 0.f, fqA1 = 0.f, fqB0 = 0.f, fqB1 = 0.f;
#pragma unroll
  for (int q = 0; q < 4; ++q) {
    float2 x;
    x = *reinterpret_cast<const float2*>(colS4 + q * DTOT + cA);
    fsA0 += x.x; fsA1 += x.y;
    x = *reinterpret_cast<const float2*>(colS4 + q * DTOT + cB);
    fsB0 += x.x; fsB1 += x.y;
    x = *reinterpret_cast<const float2*>(colQ4 + q * DTOT + cA);
    fqA0 += x.x; fqA1 += x.y;
    x = *reinterpret_cast<const float2*>(colQ4 + q * DTOT + cB);
    fqB0 += x.x; fqB1 += x.y;
  }
  const float c2 = -GAMMA_F * (float)NROWS;     // -gamma*N
  const float c1A0 = 2.f * GAMMA_F * fsA0, c1A1 = 2.f * GAMMA_F * fsA1;
  const float c1B0 = 2.f * GAMMA_F * fsB0, c1B1 = 2.f * GAMMA_F * fsB1;
  const float c0A0 = -GAMMA_F * fqA0, c0A1 = -GAMMA_F * fqA1;
  const float c0B0 = -GAMMA_F * fqB0, c0B1 = -GAMMA_F * fqB1;
  const float2 w0A = *reinterpret_cast<const float2*>(w + cA);
  const float2 w0B = *reinterpret_cast<const float2*>(w + cB);
  const float2 w1A = *reinterpret_cast<const float2*>(w + DTOT + cA);
  const float2 w1B = *reinterpret_cast<const float2*>(w + DTOT + cB);

#pragma unroll
  for (int r = 0; r < RPB; ++r) {
    const float2 va = ra[r], vb = rb[r];
    const float f0 = __expf((c2 * va.x + c1A0) * va.x + c0A0);
    const float f1 = __expf((c2 * va.y + c1A1) * va.y + c0A1);
    const float f2 = __expf((c2 * vb.x + c1B0) * vb.x + c0B0);
    const float f3 = __expf((c2 * vb.y + c1B1) * vb.y + c0B1);
    float a0 = f0 * w0A.x + f1 * w0A.y + f2 * w0B.x + f3 * w0B.y;
    float a1 = f0 * w1A.x + f1 * w1A.y + f2 * w1B.x + f3 * w1B.y;
#pragma unroll
    for (int off = 32; off; off >>= 1) {
      a0 += __shfl_down(a0, off);
      a1 += __shfl_down(a1, off);
    }
    if (ln == 0) {
      red[r][wv][0] = a0;
      red[r][wv][1] = a1;
    }
  }
  __syncthreads();
  if (t < RPB) {                          // 16 threads finalize 16 rows
    const float o0 =
        red[t][0][0] + red[t][1][0] + red[t][2][0] + red[t][3][0] + bias[0];
    const float o1 =
        red[t][0][1] + red[t][1][1] + red[t][2][1] + red[t][3][1] + bias[1];
    out[(r0 + t) * 2 + 0] = o0;
    out[(r0 + t) * 2 + 1] = o1;
  }
}

extern "C" void kernel_launch(void* const* d_in, const int* in_sizes, int n_in,
                              void* d_out, int out_size, void* d_ws,
                              size_t ws_size, hipStream_t stream) {
  const float* ts = (const float*)d_in[0];   // [16384, 1022]
  const float* m0 = (const float*)d_in[1];   // [16384]
  const float* m1 = (const float*)d_in[2];   // [16384]
  const float* w  = (const float*)d_in[3];   // [2, 1024]
  const float* bb = (const float*)d_in[4];   // [2]
  float* out = (float*)d_out;                // [16384, 2]

  float* psum  = (float*)d_ws;               // [1024][1024]
  float* psq   = psum + NBLK * DTOT;         // [1024][1024]
  float* colS4 = psq + NBLK * DTOT;          // [4][1024]
  float* colQ4 = colS4 + 4 * DTOT;           // [4][1024]
  unsigned* bar = (unsigned*)(colQ4 + 4 * DTOT);  // 2 x BARSZ u32

  // Re-zero both barrier instances every call (ws poisoned once, never
  // restored between replays).
  hipMemsetAsync(bar, 0, 2 * BARSZ * sizeof(unsigned), stream);
  svm_fused<<<dim3(NBLK), dim3(256), 0, stream>>>(
      ts, m0, m1, w, bb, psum, psq, colS4, colQ4, bar, out);
}

// Round 10
// 56.802 us; speedup vs baseline: 6.2344x; 1.0955x over previous
//
#include <hip/hip_runtime.h>

// N = 16384 rows, D_TS = 1022 ts cols, D = 1024 total cols, C = 2, GAMMA = 0.1
// Reference:
//   x = concat(ts, meta0, meta1)                 [N, 1024]
//   S[d] = sum_i x[i,d]; Q[d] = sum_i x[i,d]^2
//   pairwise_sq[i,d] = N*x^2 - 2*x*S[d] + Q[d]
//   out = exp(-GAMMA*pairwise_sq) @ w.T + b      [N, 2] fp32
//
// Round-10: broadcast-tree barrier release. Barrier history:
//   r6 354us: acquire-per-poll -> buffer_inv storm (L2 wiped chip-wide).
//   r7 218us: release/acquire per block -> 2048 whole-L2 wbl2/inv ops.
//   r8 134us: clean, but 1024 RMWs on one line = ~55us serial chain/barrier.
//   r9  62us: hierarchical arrivals fixed RMWs, but 1024 spinners polling ONE
//             root line queue the home-L2 bank; the 32 root increments queue
//             BEHIND the spin reads -> ~22us/barrier.
//   r10: arrivals stay 32x32 hierarchical; last root-arriver FANS OUT 32
//        relaxed stores to per-group release lines; each leader spins on its
//        own group's line (32 spinners/line, release path uncontended).
// Cross-barrier data: agent-scope RELAXED atomic stores (write-through, never
// dirty in L2) + s_waitcnt vmcnt(0) before arrival; consumers use normal
// cached loads (first in-dispatch touch misses to fabric). Validated r8/r9.
// 1024 blocks x 256 thr, __launch_bounds__(256,4), LDS 2.5 KB -> 4 blocks/CU
// x 256 CU = 1024 co-resident; spin barrier cannot deadlock.

#define NROWS   16384
#define DTS     1022
#define DTOT    1024
#define NBLK    1024
#define RPB     16                  // rows per block
#define GAMMA_F 0.1f
#define NGRP    32                  // barrier groups (32 blocks each)
#define GPB     (NBLK / NGRP)       // blocks per group = 32
#define GSTRIDE 32                  // u32 stride between counter lines (128B)
#define BARSZ   4096                // u32 slots per barrier instance (16KB)
// Layout per instance: gcnt[g] @ g*32, grel[g] @ 1024+g*32, root @ 2080.

// Agent-scope relaxed (write-through, no cache maintenance) 8-byte store.
__device__ __forceinline__ void st_f2_agent(float* p, float2 v) {
  __hip_atomic_store(reinterpret_cast<unsigned long long*>(p),
                     __builtin_bit_cast(unsigned long long, v),
                     __ATOMIC_RELAXED, __HIP_MEMORY_SCOPE_AGENT);
}

__device__ __forceinline__ void grid_barrier(unsigned* base, int grp) {
  __syncthreads();                  // block done with its phase
  if (threadIdx.x == 0) {
    asm volatile("s_waitcnt vmcnt(0)" ::: "memory");  // drain write-throughs
    unsigned* gcnt = base + grp * GSTRIDE;
    unsigned* grel = base + 1024 + grp * GSTRIDE;
    unsigned* root = base + 2080;
    const unsigned old = __hip_atomic_fetch_add(gcnt, 1u, __ATOMIC_RELAXED,
                                                __HIP_MEMORY_SCOPE_AGENT);
    if (old == GPB - 1u) {                // last arriver of this group
      const unsigned r = __hip_atomic_fetch_add(
          root, 1u, __ATOMIC_RELAXED, __HIP_MEMORY_SCOPE_AGENT);
      if (r == NGRP - 1u) {               // last group: broadcast release
#pragma unroll
        for (int g = 0; g < NGRP; ++g) {
          __hip_atomic_store(base + 1024 + g * GSTRIDE, 1u, __ATOMIC_RELAXED,
                             __HIP_MEMORY_SCOPE_AGENT);
        }
      }
    }
    // Spin on THIS group's release line: 32 spinners/line, no RMW traffic.
    while (__hip_atomic_load(grel, __ATOMIC_RELAXED,
                             __HIP_MEMORY_SCOPE_AGENT) == 0u) {
      __builtin_amdgcn_s_sleep(16);
    }
  }
  __syncthreads();
}

__global__ __launch_bounds__(256, 4) void svm_fused(
    const float* __restrict__ ts, const float* __restrict__ m0,
    const float* __restrict__ m1, const float* __restrict__ w,
    const float* __restrict__ bias, float* __restrict__ psum,
    float* __restrict__ psq, float* __restrict__ colS4,
    float* __restrict__ colQ4, unsigned* __restrict__ bar,
    float* __restrict__ out) {
  __shared__ float red[RPB][4][2];        // 512 B: per-row per-wave partials
  __shared__ float ls[4][64], lq[4][64];  // 2 KB: phase-2 scratch

  const int b  = blockIdx.x;
  const int t  = threadIdx.x;
  const int wv = t >> 6, ln = t & 63;
  const int r0 = b * RPB;
  const int grp = b >> 5;                 // 32 consecutive blocks per group
  const int cA = 2 * t;                   // cols 0..510   (even)
  const int cB = 512 + 2 * t;             // cols 512..1022 (1022 -> meta)

  // ---- Phase 1: read this block's 16 rows; accumulate 4-col partials;
  //      write-through to psum/psq.
  float2 ra[RPB], rb[RPB];
  float sA0 = 0.f, sA1 = 0.f, qA0 = 0.f, qA1 = 0.f;
  float sB0 = 0.f, sB1 = 0.f, qB0 = 0.f, qB1 = 0.f;
#pragma unroll
  for (int r = 0; r < RPB; ++r) {
    const int i = r0 + r;
    const float* row = ts + (size_t)i * DTS;
    float2 va = *reinterpret_cast<const float2*>(row + cA);
    float2 vb;
    if (cB < DTS) {
      vb = *reinterpret_cast<const float2*>(row + cB);
    } else {                              // cB == 1022: metadata columns
      vb = make_float2(m0[i], m1[i]);
    }
    ra[r] = va;
    rb[r] = vb;
    sA0 += va.x; sA1 += va.y; qA0 += va.x * va.x; qA1 += va.y * va.y;
    sB0 += vb.x; sB1 += vb.y; qB0 += vb.x * vb.x; qB1 += vb.y * vb.y;
  }
  st_f2_agent(psum + b * DTOT + cA, make_float2(sA0, sA1));
  st_f2_agent(psum + b * DTOT + cB, make_float2(sB0, sB1));
  st_f2_agent(psq  + b * DTOT + cA, make_float2(qA0, qA1));
  st_f2_agent(psq  + b * DTOT + cB, make_float2(qB0, qB1));

  grid_barrier(bar, grp);

  // ---- Phase 2: 64 blocks reduce psum/psq[1024][1024] -> quarters [4][1024].
  // Block b<64: col-group g=b&15 (64 cols, lane<->col coalesced), quarter
  // q=b>>4 (256 chunks). Normal cached loads (first in-dispatch touch).
  if (b < 64) {
    const int g = b & 15, q = b >> 4;
    const int c = g * 64 + ln;
    float s = 0.f, qq = 0.f;
#pragma unroll 16
    for (int ch = q * 256 + wv; ch < (q + 1) * 256; ch += 4) {
      s  += psum[ch * DTOT + c];
      qq += psq[ch * DTOT + c];
    }
    ls[wv][ln] = s;
    lq[wv][ln] = qq;
    __syncthreads();
    if (wv == 0) {
      const float S = ls[0][ln] + ls[1][ln] + ls[2][ln] + ls[3][ln];
      const float Q = lq[0][ln] + lq[1][ln] + lq[2][ln] + lq[3][ln];
      __hip_atomic_store(colS4 + q * DTOT + c, S, __ATOMIC_RELAXED,
                         __HIP_MEMORY_SCOPE_AGENT);
      __hip_atomic_store(colQ4 + q * DTOT + c, Q, __ATOMIC_RELAXED,
                         __HIP_MEMORY_SCOPE_AGENT);
    }
  }

  grid_barrier(bar + BARSZ, grp);

  // ---- Phase 3: fold quarters for this thread's 4 columns, 16 rows of
  //      exp+dot from the register cache, block-wide reduce, 16 rows out.
  float fsA0 = 0.f, fsA1 = 0.f, fsB0 = 0.f, fsB1 = 0.f;
  float fqA0 = 0.f, fqA1 = 0.f, fqB0 = 0.f, fqB1 = 0.f;
#pragma unroll
  for (int q = 0; q < 4; ++q) {
    float2 x;
    x = *reinterpret_cast<const float2*>(colS4 + q * DTOT + cA);
    fsA0 += x.x; fsA1 += x.y;
    x = *reinterpret_cast<const float2*>(colS4 + q * DTOT + cB);
    fsB0 += x.x; fsB1 += x.y;
    x = *reinterpret_cast<const float2*>(colQ4 + q * DTOT + cA);
    fqA0 += x.x; fqA1 += x.y;
    x = *reinterpret_cast<const float2*>(colQ4 + q * DTOT + cB);
    fqB0 += x.x; fqB1 += x.y;
  }
  const float c2 = -GAMMA_F * (float)NROWS;     // -gamma*N
  const float c1A0 = 2.f * GAMMA_F * fsA0, c1A1 = 2.f * GAMMA_F * fsA1;
  const float c1B0 = 2.f * GAMMA_F * fsB0, c1B1 = 2.f * GAMMA_F * fsB1;
  const float c0A0 = -GAMMA_F * fqA0, c0A1 = -GAMMA_F * fqA1;
  const float c0B0 = -GAMMA_F * fqB0, c0B1 = -GAMMA_F * fqB1;
  const float2 w0A = *reinterpret_cast<const float2*>(w + cA);
  const float2 w0B = *reinterpret_cast<const float2*>(w + cB);
  const float2 w1A = *reinterpret_cast<const float2*>(w + DTOT + cA);
  const float2 w1B = *reinterpret_cast<const float2*>(w + DTOT + cB);

#pragma unroll
  for (int r = 0; r < RPB; ++r) {
    const float2 va = ra[r], vb = rb[r];
    const float f0 = __expf((c2 * va.x + c1A0) * va.x + c0A0);
    const float f1 = __expf((c2 * va.y + c1A1) * va.y + c0A1);
    const float f2 = __expf((c2 * vb.x + c1B0) * vb.x + c0B0);
    const float f3 = __expf((c2 * vb.y + c1B1) * vb.y + c0B1);
    float a0 = f0 * w0A.x + f1 * w0A.y + f2 * w0B.x + f3 * w0B.y;
    float a1 = f0 * w1A.x + f1 * w1A.y + f2 * w1B.x + f3 * w1B.y;
#pragma unroll
    for (int off = 32; off; off >>= 1) {
      a0 += __shfl_down(a0, off);
      a1 += __shfl_down(a1, off);
    }
    if (ln == 0) {
      red[r][wv][0] = a0;
      red[r][wv][1] = a1;
    }
  }
  __syncthreads();
  if (t < RPB) {                          // 16 threads finalize 16 rows
    const float o0 =
        red[t][0][0] + red[t][1][0] + red[t][2][0] + red[t][3][0] + bias[0];
    const float o1 =
        red[t][0][1] + red[t][1][1] + red[t][2][1] + red[t][3][1] + bias[1];
    out[(r0 + t) * 2 + 0] = o0;
    out[(r0 + t) * 2 + 1] = o1;
  }
}

extern "C" void kernel_launch(void* const* d_in, const int* in_sizes, int n_in,
                              void* d_out, int out_size, void* d_ws,
                              size_t ws_size, hipStream_t stream) {
  const float* ts = (const float*)d_in[0];   // [16384, 1022]
  const float* m0 = (const float*)d_in[1];   // [16384]
  const float* m1 = (const float*)d_in[2];   // [16384]
  const float* w  = (const float*)d_in[3];   // [2, 1024]
  const float* bb = (const float*)d_in[4];   // [2]
  float* out = (float*)d_out;                // [16384, 2]

  float* psum  = (float*)d_ws;               // [1024][1024]
  float* psq   = psum + NBLK * DTOT;         // [1024][1024]
  float* colS4 = psq + NBLK * DTOT;          // [4][1024]
  float* colQ4 = colS4 + 4 * DTOT;           // [4][1024]
  unsigned* bar = (unsigned*)(colQ4 + 4 * DTOT);  // 2 x BARSZ u32 (32 KB)

  // Re-zero both barrier instances every call (ws poisoned once, never
  // restored between replays).
  hipMemsetAsync(bar, 0, 2 * BARSZ * sizeof(unsigned), stream);
  svm_fused<<<dim3(NBLK), dim3(256), 0, stream>>>(
      ts, m0, m1, w, bb, psum, psq, colS4, colQ4, bar, out);
}

// Round 11
// 39.016 us; speedup vs baseline: 9.0766x; 1.4559x over previous
//
#include <hip/hip_runtime.h>

// N = 16384 rows, D_TS = 1022 ts cols, D = 1024 total cols, C = 2, GAMMA = 0.1
// Reference:
//   x = concat(ts, meta0, meta1)                 [N, 1024]
//   S[d] = sum_i x[i,d]; Q[d] = sum_i x[i,d]^2
//   pairwise_sq[i,d] = N*x^2 - 2*x*S[d] + Q[d]
//   out = exp(-GAMMA*pairwise_sq) @ w.T + b      [N, 2] fp32
//
// Round-11: back to 3 plain kernels. Fused-barrier line (r6-r10) bottomed at
// 57us: a 1024-block grid barrier costs ~15-20us minimum on this chip
// (arrival chains + fabric spin traffic), and the register row-cache never
// materialized (VGPR=60 -> compiler re-reads ts in phase 3 regardless), so
// fusion had no data-reuse payoff. 3-kernel r4 was 34us; this round applies
// the fused-line learnings to it:
//   K1: full-row streaming (16 contiguous rows/block, 64KB contig reads).
//   K2: 64-block parallel reduce -> quarters colS4/colQ4[4][1024].
//   K3: zero-LDS register constants w/ quarter fold (r3/r4 form).
// Entire input (64MB) is L3-resident across replays (FETCH ~38MB), so the
// roofline is fabric/L3 BW: ~145MB traffic ~16-18us + 2 launch gaps.
// History: r2 atomics=44, r4=34, r5 coop=FAIL, r6=354, r7=218, r8=134,
//          r9=62, r10=57.

#define NROWS   16384
#define DTS     1022
#define DTOT    1024
#define NBLK    1024                // K1 blocks = chunks
#define RPB     16                  // rows per K1 block
#define GAMMA_F 0.1f

// ---------------------------------------------------------------------------
// K1: per-block column sums/sq-sums over 16 CONTIGUOUS rows (64KB contiguous
// stream per block). Thread owns cols {2t,2t+1,512+2t,513+2t}; t==255's B
// pair is the metadata columns. Writes one chunk row of psum/psq.
// ---------------------------------------------------------------------------
__global__ __launch_bounds__(256) void colsum_partial(
    const float* __restrict__ ts, const float* __restrict__ m0,
    const float* __restrict__ m1, float* __restrict__ psum,
    float* __restrict__ psq) {
  const int b  = blockIdx.x;              // 0..1023
  const int t  = threadIdx.x;
  const int r0 = b * RPB;
  const int cA = 2 * t;                   // 0..510
  const int cB = 512 + 2 * t;             // 512..1022 (1022 -> meta)

  float sA0 = 0.f, sA1 = 0.f, qA0 = 0.f, qA1 = 0.f;
  float sB0 = 0.f, sB1 = 0.f, qB0 = 0.f, qB1 = 0.f;
#pragma unroll 4
  for (int r = 0; r < RPB; ++r) {
    const int i = r0 + r;
    const float* row = ts + (size_t)i * DTS;
    const float2 va = *reinterpret_cast<const float2*>(row + cA);
    float2 vb;
    if (cB < DTS) {
      vb = *reinterpret_cast<const float2*>(row + cB);
    } else {                              // cB == 1022: metadata columns
      vb = make_float2(m0[i], m1[i]);
    }
    sA0 += va.x; sA1 += va.y; qA0 += va.x * va.x; qA1 += va.y * va.y;
    sB0 += vb.x; sB1 += vb.y; qB0 += vb.x * vb.x; qB1 += vb.y * vb.y;
  }
  *reinterpret_cast<float2*>(psum + b * DTOT + cA) = make_float2(sA0, sA1);
  *reinterpret_cast<float2*>(psum + b * DTOT + cB) = make_float2(sB0, sB1);
  *reinterpret_cast<float2*>(psq  + b * DTOT + cA) = make_float2(qA0, qA1);
  *reinterpret_cast<float2*>(psq  + b * DTOT + cB) = make_float2(qB0, qB1);
}

// ---------------------------------------------------------------------------
// K2: 64-block parallel reduce of psum/psq[1024][1024] -> quarters [4][1024].
// Block b: col-group g=b&15 (64 cols, lane<->col coalesced 256B/wave),
// quarter q=b>>4 (256 chunks; wave wv strides 4). LDS combine across 4 waves.
// ---------------------------------------------------------------------------
__global__ __launch_bounds__(256) void colsum_reduce(
    const float* __restrict__ psum, const float* __restrict__ psq,
    float* __restrict__ colS4, float* __restrict__ colQ4) {
  __shared__ float ls[4][64], lq[4][64];
  const int b  = blockIdx.x;              // 0..63
  const int g  = b & 15, q = b >> 4;
  const int wv = threadIdx.x >> 6, ln = threadIdx.x & 63;
  const int c  = g * 64 + ln;             // 0..1023

  float s = 0.f, qq = 0.f;
#pragma unroll 16
  for (int ch = q * 256 + wv; ch < (q + 1) * 256; ch += 4) {
    s  += psum[ch * DTOT + c];
    qq += psq[ch * DTOT + c];
  }
  ls[wv][ln] = s;
  lq[wv][ln] = qq;
  __syncthreads();
  if (wv == 0) {
    colS4[q * DTOT + c] = ls[0][ln] + ls[1][ln] + ls[2][ln] + ls[3][ln];
    colQ4[q * DTOT + c] = lq[0][ln] + lq[1][ln] + lq[2][ln] + lq[3][ln];
  }
}

// ---------------------------------------------------------------------------
// K3: fused feat + GEMV, zero LDS. 1024 blocks x 256 thr (4 waves); wave
// handles 4 consecutive rows. Lane's 16 fixed columns (d = k*128 + ln*2):
// fold colS4/colQ4 quarters + load w into 64 registers once, then per row:
// 8 float2 loads (L3) + exp/FMA + 64-lane butterfly, lane 0 writes 2 floats.
// ---------------------------------------------------------------------------
__global__ __launch_bounds__(256) void svm_logits(
    const float* __restrict__ ts, const float* __restrict__ m0,
    const float* __restrict__ m1, const float* __restrict__ w,
    const float* __restrict__ bias, const float* __restrict__ colS4,
    const float* __restrict__ colQ4, float* __restrict__ out) {
  const int t  = threadIdx.x;
  const int wv = t >> 6, ln = t & 63;
  const float b0 = bias[0], b1 = bias[1];     // uniform -> scalar loads
  const float c2 = -GAMMA_F * (float)NROWS;   // -gamma*N

  float c1x[8], c1y[8], c0x[8], c0y[8];
  float w0x[8], w0y[8], w1x[8], w1y[8];
#pragma unroll
  for (int k = 0; k < 8; ++k) {
    const int d = k * 128 + ln * 2;           // even, 0..1022
    float sx = 0.f, sy = 0.f, qx = 0.f, qy = 0.f;
#pragma unroll
    for (int q = 0; q < 4; ++q) {
      const float2 cs = *reinterpret_cast<const float2*>(colS4 + q * DTOT + d);
      const float2 cq = *reinterpret_cast<const float2*>(colQ4 + q * DTOT + d);
      sx += cs.x; sy += cs.y; qx += cq.x; qy += cq.y;
    }
    c1x[k] = 2.0f * GAMMA_F * sx;
    c1y[k] = 2.0f * GAMMA_F * sy;
    c0x[k] = -GAMMA_F * qx;
    c0y[k] = -GAMMA_F * qy;
    const float2 v0 = *reinterpret_cast<const float2*>(w + d);
    const float2 v1 = *reinterpret_cast<const float2*>(w + DTOT + d);
    w0x[k] = v0.x; w0y[k] = v0.y;
    w1x[k] = v1.x; w1y[k] = v1.y;
  }

  const int gw = blockIdx.x * 4 + wv;         // 0..4095
#pragma unroll
  for (int rr = 0; rr < 4; ++rr) {
    const int i = gw * 4 + rr;                // row, < 16384
    const float* row = ts + (size_t)i * DTS;
    float acc0 = 0.f, acc1 = 0.f;
#pragma unroll
    for (int k = 0; k < 8; ++k) {
      const int d = k * 128 + ln * 2;
      float x0, x1;
      if (d < DTS) {
        const float2 v = *reinterpret_cast<const float2*>(row + d);
        x0 = v.x; x1 = v.y;
      } else {                                // d == 1022 -> meta columns
        x0 = m0[i]; x1 = m1[i];
      }
      const float f0 = __expf((c2 * x0 + c1x[k]) * x0 + c0x[k]);
      const float f1 = __expf((c2 * x1 + c1y[k]) * x1 + c0y[k]);
      acc0 += f0 * w0x[k] + f1 * w0y[k];
      acc1 += f0 * w1x[k] + f1 * w1y[k];
    }
#pragma unroll
    for (int off = 32; off; off >>= 1) {
      acc0 += __shfl_down(acc0, off);
      acc1 += __shfl_down(acc1, off);
    }
    if (ln == 0) {
      out[i * 2 + 0] = acc0 + b0;
      out[i * 2 + 1] = acc1 + b1;
    }
  }
}

extern "C" void kernel_launch(void* const* d_in, const int* in_sizes, int n_in,
                              void* d_out, int out_size, void* d_ws,
                              size_t ws_size, hipStream_t stream) {
  const float* ts = (const float*)d_in[0];   // [16384, 1022]
  const float* m0 = (const float*)d_in[1];   // [16384]
  const float* m1 = (const float*)d_in[2];   // [16384]
  const float* w  = (const float*)d_in[3];   // [2, 1024]
  const float* bb = (const float*)d_in[4];   // [2]
  float* out = (float*)d_out;                // [16384, 2]

  float* psum  = (float*)d_ws;               // [1024][1024] (4 MB)
  float* psq   = psum + NBLK * DTOT;         // [1024][1024] (4 MB)
  float* colS4 = psq + NBLK * DTOT;          // [4][1024]
  float* colQ4 = colS4 + 4 * DTOT;           // [4][1024]

  colsum_partial<<<dim3(NBLK), 256, 0, stream>>>(ts, m0, m1, psum, psq);
  colsum_reduce<<<dim3(64), 256, 0, stream>>>(psum, psq, colS4, colQ4);
  svm_logits<<<dim3(1024), 256, 0, stream>>>(ts, m0, m1, w, bb, colS4, colQ4,
                                             out);
}

// Round 12
// 35.290 us; speedup vs baseline: 10.0350x; 1.1056x over previous
//
#include <hip/hip_runtime.h>

// N = 16384 rows, D_TS = 1022 ts cols, D = 1024 total cols, C = 2, GAMMA = 0.1
// Reference:
//   x = concat(ts, meta0, meta1)                 [N, 1024]
//   S[d] = sum_i x[i,d]; Q[d] = sum_i x[i,d]^2
//   pairwise_sq[i,d] = N*x^2 - 2*x*S[d] + Q[d]
//   out = exp(-GAMMA*pairwise_sq) @ w.T + b      [N, 2] fp32
//
// Round-12: r4's exact proven structure (34us) + two targeted K3 changes:
//   (1) exp2 constant folding (log2e into c2/c1/c0: kills 1 mul/element),
//   (2) 3-buffer software pipeline (24 loads in flight before first use;
//       row compute overlaps next row's L3 latency; all static indices).
// Lessons kept: no atomics to hot lines (r2), no grid barriers (r6-r10 ~15-20
// us minimum each), K2 16x1024 parallel reduce, K3 quarter-fold removed (r11
// +100MB L2 preload traffic regression).
// History: r2=44(atomics), r4=34, r5 coop=FAIL, r6=354, r7=218, r8=134,
//          r9=62, r10=57, r11=39.

#define NROWS   16384
#define DTS     1022
#define DTOT    1024
#define NCHUNK  512                 // K1 row chunks; grid (2, 512)
#define RPC     (NROWS / NCHUNK)    // 32 rows per chunk
#define GAMMA_F 0.1f
#define L2E     1.4426950408889634f

// ---------------------------------------------------------------------------
// K1 (r4-exact): per-chunk column sums/sq-sums. grid = (2 col-tiles, 512),
// 256 thr. Thread owns 2 adjacent columns (float2, 8B-aligned: row stride
// 1022 floats) x 32 rows; one float2 store per array. No atomics.
// ---------------------------------------------------------------------------
__global__ __launch_bounds__(256) void colsum_partial(
    const float* __restrict__ ts, const float* __restrict__ m0,
    const float* __restrict__ m1, float* __restrict__ psum,
    float* __restrict__ psq) {
  const int tile  = blockIdx.x;                    // 0..1
  const int chunk = blockIdx.y;                    // 0..511
  const int d     = tile * 512 + threadIdx.x * 2;  // even, 0..1022
  const int r0    = chunk * RPC;

  float s0 = 0.f, s1 = 0.f, q0 = 0.f, q1 = 0.f;
  if (d < DTS) {
    const float* p = ts + (size_t)r0 * DTS + d;
#pragma unroll 8
    for (int r = 0; r < RPC; ++r) {
      const float2 v = *reinterpret_cast<const float2*>(p);
      s0 += v.x; s1 += v.y;
      q0 += v.x * v.x; q1 += v.y * v.y;
      p += DTS;
    }
  } else {  // d == 1022: metadata columns
#pragma unroll 8
    for (int r = 0; r < RPC; ++r) {
      const float a = m0[r0 + r], b = m1[r0 + r];
      s0 += a; s1 += b;
      q0 += a * a; q1 += b * b;
    }
  }
  const int o = chunk * DTOT + d;
  *reinterpret_cast<float2*>(psum + o) = make_float2(s0, s1);
  *reinterpret_cast<float2*>(psq + o)  = make_float2(q0, q1);
}

// ---------------------------------------------------------------------------
// K2 (r4-exact): 16 blocks x 1024 thr (16 waves). Block owns 64 consecutive
// columns; lane <-> column (coalesced 256B/wave-load); wave wv strides chunks
// wv, wv+16, ... (32 each); LDS combine across 16 waves. Final colS/colQ.
// ---------------------------------------------------------------------------
__global__ __launch_bounds__(1024) void colsum_final(
    const float* __restrict__ psum, const float* __restrict__ psq,
    float* __restrict__ colS, float* __restrict__ colQ) {
  const int wave = threadIdx.x >> 6, lane = threadIdx.x & 63;  // wave 0..15
  const int c = blockIdx.x * 64 + lane;  // 0..1023
  float s = 0.f, q = 0.f;
#pragma unroll 8
  for (int ch = wave; ch < NCHUNK; ch += 16) {
    s += psum[ch * DTOT + c];
    q += psq[ch * DTOT + c];
  }
  __shared__ float ls[16][64], lq[16][64];
  ls[wave][lane] = s;
  lq[wave][lane] = q;
  __syncthreads();
  if (threadIdx.x < 64) {
    float S = 0.f, Q = 0.f;
#pragma unroll
    for (int k = 0; k < 16; ++k) {
      S += ls[k][lane];
      Q += lq[k][lane];
    }
    colS[c] = S;
    colQ[c] = Q;
  }
}

// ---------------------------------------------------------------------------
// K3 helpers: row load (8 float2, lane's 16 fixed cols), row dot (exp2 form),
// wave reduce + store. All loops statically unrolled (no scratch, rule #20).
// ---------------------------------------------------------------------------
__device__ __forceinline__ void load_row(const float* __restrict__ ts,
                                         const float* __restrict__ m0,
                                         const float* __restrict__ m1, int i,
                                         int ln, float2 (&buf)[8]) {
#pragma unroll
  for (int k = 0; k < 8; ++k) {
    const int d = k * 128 + ln * 2;       // even, 0..1022
    if (d < DTS) {
      buf[k] = *reinterpret_cast<const float2*>(ts + (size_t)i * DTS + d);
    } else {                              // d == 1022 -> meta columns
      buf[k] = make_float2(m0[i], m1[i]);
    }
  }
}

__device__ __forceinline__ void row_dot(
    const float2 (&v)[8], float p2, const float (&c1x)[8],
    const float (&c1y)[8], const float (&c0x)[8], const float (&c0y)[8],
    const float (&w0x)[8], const float (&w0y)[8], const float (&w1x)[8],
    const float (&w1y)[8], float& acc0, float& acc1) {
  acc0 = 0.f;
  acc1 = 0.f;
#pragma unroll
  for (int k = 0; k < 8; ++k) {
    const float f0 = exp2f((p2 * v[k].x + c1x[k]) * v[k].x + c0x[k]);
    const float f1 = exp2f((p2 * v[k].y + c1y[k]) * v[k].y + c0y[k]);
    acc0 += f0 * w0x[k] + f1 * w0y[k];
    acc1 += f0 * w1x[k] + f1 * w1y[k];
  }
}

__device__ __forceinline__ void reduce_store(float acc0, float acc1, int ln,
                                             float b0, float b1,
                                             float* __restrict__ out, int i) {
#pragma unroll
  for (int off = 32; off; off >>= 1) {
    acc0 += __shfl_down(acc0, off);
    acc1 += __shfl_down(acc1, off);
  }
  if (ln == 0) {
    out[i * 2 + 0] = acc0 + b0;
    out[i * 2 + 1] = acc1 + b1;
  }
}

// ---------------------------------------------------------------------------
// K3: fused feat + GEMV, zero LDS. 1024 blocks x 256 thr (4 waves); wave
// handles 4 consecutive rows via 3-buffer pipeline (A,B,C preloaded -> 24
// loads in flight; A reloaded for row 3 behind row-0/1 compute).
// Constants in registers, pre-scaled by log2e so f = exp2(poly) directly.
// ---------------------------------------------------------------------------
__global__ __launch_bounds__(256) void svm_logits(
    const float* __restrict__ ts, const float* __restrict__ m0,
    const float* __restrict__ m1, const float* __restrict__ w,
    const float* __restrict__ bias, const float* __restrict__ colS,
    const float* __restrict__ colQ, float* __restrict__ out) {
  const int t  = threadIdx.x;
  const int wv = t >> 6, ln = t & 63;
  const float b0 = bias[0], b1 = bias[1];           // uniform -> scalar loads
  const float p2 = -GAMMA_F * (float)NROWS * L2E;   // -gamma*N*log2e

  float c1x[8], c1y[8], c0x[8], c0y[8];
  float w0x[8], w0y[8], w1x[8], w1y[8];
#pragma unroll
  for (int k = 0; k < 8; ++k) {
    const int d = k * 128 + ln * 2;                 // even, 0..1022
    const float2 cs = *reinterpret_cast<const float2*>(colS + d);
    const float2 cq = *reinterpret_cast<const float2*>(colQ + d);
    const float2 v0 = *reinterpret_cast<const float2*>(w + d);
    const float2 v1 = *reinterpret_cast<const float2*>(w + DTOT + d);
    c1x[k] = 2.0f * GAMMA_F * L2E * cs.x;
    c1y[k] = 2.0f * GAMMA_F * L2E * cs.y;
    c0x[k] = -GAMMA_F * L2E * cq.x;
    c0y[k] = -GAMMA_F * L2E * cq.y;
    w0x[k] = v0.x; w0y[k] = v0.y;
    w1x[k] = v1.x; w1y[k] = v1.y;
  }

  const int i0 = (blockIdx.x * 4 + wv) * 4;         // first of 4 rows
  float2 A[8], B[8], C[8];
  float a0, a1;
  load_row(ts, m0, m1, i0 + 0, ln, A);
  load_row(ts, m0, m1, i0 + 1, ln, B);
  load_row(ts, m0, m1, i0 + 2, ln, C);

  row_dot(A, p2, c1x, c1y, c0x, c0y, w0x, w0y, w1x, w1y, a0, a1);
  load_row(ts, m0, m1, i0 + 3, ln, A);              // refill behind compute
  reduce_store(a0, a1, ln, b0, b1, out, i0 + 0);

  row_dot(B, p2, c1x, c1y, c0x, c0y, w0x, w0y, w1x, w1y, a0, a1);
  reduce_store(a0, a1, ln, b0, b1, out, i0 + 1);

  row_dot(C, p2, c1x, c1y, c0x, c0y, w0x, w0y, w1x, w1y, a0, a1);
  reduce_store(a0, a1, ln, b0, b1, out, i0 + 2);

  row_dot(A, p2, c1x, c1y, c0x, c0y, w0x, w0y, w1x, w1y, a0, a1);
  reduce_store(a0, a1, ln, b0, b1, out, i0 + 3);
}

extern "C" void kernel_launch(void* const* d_in, const int* in_sizes, int n_in,
                              void* d_out, int out_size, void* d_ws,
                              size_t ws_size, hipStream_t stream) {
  const float* ts = (const float*)d_in[0];   // [16384, 1022]
  const float* m0 = (const float*)d_in[1];   // [16384]
  const float* m1 = (const float*)d_in[2];   // [16384]
  const float* w  = (const float*)d_in[3];   // [2, 1024]
  const float* bb = (const float*)d_in[4];   // [2]
  float* out = (float*)d_out;                // [16384, 2]

  float* psum = (float*)d_ws;                // [512][1024] (2 MB)
  float* psq  = psum + NCHUNK * DTOT;        // [512][1024] (2 MB)
  float* colS = psq + NCHUNK * DTOT;         // [1024]
  float* colQ = colS + DTOT;                 // [1024]

  colsum_partial<<<dim3(2, NCHUNK), 256, 0, stream>>>(ts, m0, m1, psum, psq);
  colsum_final<<<dim3(16), 1024, 0, stream>>>(psum, psq, colS, colQ);
  svm_logits<<<dim3(1024), 256, 0, stream>>>(ts, m0, m1, w, bb, colS, colQ,
                                             out);
}